// Round 3
// baseline (333.055 us; speedup 1.0000x reference)
//
#include <hip/hip_runtime.h>
#include <math.h>

typedef __attribute__((ext_vector_type(8))) short short8;
typedef __attribute__((ext_vector_type(4))) float f32x4;

#define NN 10000
#define EE 320000
#define NHEAD 16
#define EPSf 1e-5f

// ---------- bf16 helpers ----------
__device__ __forceinline__ unsigned short f2bf(float f) {
    union { float f; unsigned u; } v; v.f = f;
    unsigned u = v.u;
    u += 0x7fffu + ((u >> 16) & 1u);   // RNE
    return (unsigned short)(u >> 16);
}
__device__ __forceinline__ unsigned pk2(float a, float b) {
    return ((unsigned)f2bf(b) << 16) | (unsigned)f2bf(a);
}

// ---------------------- init: denom/0, out/0 ----------------------
__global__ void k_init(float* __restrict__ denom, float* __restrict__ out) {
    int i = blockIdx.x * 256 + threadIdx.x;
    if (i < NN * NHEAD) denom[i] = 0.f;
    if (i < NN * 3) out[i] = 0.f;
}

// ------------- prep: bf16-convert h; transpose+bf16+K-permute weights -------------
// kv layout (k'): [0..127]=h_dst, [128..255]=h_src, [256..259]=ea, [260..339]=dist, [340..383]=0
__global__ void k_prep(const float* __restrict__ h,
                       const float* __restrict__ kW1, const float* __restrict__ vW1,
                       const float* __restrict__ kW2, const float* __restrict__ vW2,
                       unsigned short* __restrict__ h_bf, unsigned short* __restrict__ Wt1,
                       unsigned short* __restrict__ kW2t, unsigned short* __restrict__ vW2t) {
    int i = blockIdx.x * 256 + threadIdx.x;
    if (i < NN * 128) { h_bf[i] = f2bf(h[i]); return; }
    int j = i - NN * 128;
    if (j < 256 * 352) {
        int n = j / 352, k = j % 352;
        float val = 0.f;
        if (k < 340) {
            int pk;
            if (k < 128)      pk = 84 + k;
            else if (k < 256) pk = 212 + (k - 128);
            else if (k < 260) pk = k - 256;
            else              pk = 4 + (k - 260);
            val = (n < 128) ? kW1[pk * 128 + n] : vW1[pk * 128 + (n - 128)];
        }
        Wt1[j] = f2bf(val); return;
    }
    j -= 256 * 352;
    if (j < 128 * 128) { int n = j >> 7, k = j & 127; kW2t[j] = f2bf(kW2[k * 128 + n]); return; }
    j -= 128 * 128;
    if (j < 16 * 128)  { int n = j >> 7, k = j & 127; vW2t[j] = f2bf(vW2[k * 16 + n]); return; }
}

// ---------------------- q = MLP(h) in f32 (small) ----------------------
__global__ __launch_bounds__(256) void k_qmlp(
    const float* __restrict__ h,
    const float* __restrict__ W1, const float* __restrict__ b1,
    const float* __restrict__ g,  const float* __restrict__ bt,
    const float* __restrict__ W2, const float* __restrict__ b2,
    float* __restrict__ q)
{
    __shared__ float sH[32 * 128];
    __shared__ float sY[32 * 128];
    const int tid = threadIdx.x;
    const int n0 = blockIdx.x * 32;

    #pragma unroll
    for (int j = 0; j < 4; ++j) {
        int p = tid + j * 256;
        int e = p >> 5, i = p & 31;
        int node = n0 + e; if (node >= NN) node = NN - 1;
        float4 v = *(const float4*)(h + node * 128 + i * 4);
        *(float4*)(sH + e * 128 + i * 4) = v;
    }
    __syncthreads();

    const int c  = tid & 127;
    const int eg = (tid >> 7) * 16;
    float acc[16];
    #pragma unroll
    for (int e = 0; e < 16; ++e) acc[e] = 0.f;
    for (int k = 0; k < 128; k += 4) {
        float w0 = W1[(k + 0) * 128 + c], w1 = W1[(k + 1) * 128 + c];
        float w2 = W1[(k + 2) * 128 + c], w3 = W1[(k + 3) * 128 + c];
        #pragma unroll
        for (int e = 0; e < 16; ++e) {
            float4 a = *(const float4*)(sH + (eg + e) * 128 + k);
            acc[e] += a.x * w0 + a.y * w1 + a.z * w2 + a.w * w3;
        }
    }
    {
        float bb = b1[c];
        #pragma unroll
        for (int e = 0; e < 16; ++e) sY[(eg + e) * 128 + c] = acc[e] + bb;
    }
    __syncthreads();

    {
        int r = tid >> 3, s = tid & 7;
        float* row = sY + r * 128;
        float vals[16];
        float sum = 0.f, sq = 0.f;
        #pragma unroll
        for (int j = 0; j < 4; ++j) {
            float4 v = *(float4*)(row + s * 16 + j * 4);
            vals[j*4+0] = v.x; vals[j*4+1] = v.y; vals[j*4+2] = v.z; vals[j*4+3] = v.w;
        }
        #pragma unroll
        for (int j = 0; j < 16; ++j) { sum += vals[j]; sq += vals[j] * vals[j]; }
        #pragma unroll
        for (int o = 1; o < 8; o <<= 1) { sum += __shfl_xor(sum, o, 64); sq += __shfl_xor(sq, o, 64); }
        float mu = sum * (1.f / 128.f);
        float var = sq * (1.f / 128.f) - mu * mu;
        float rs = rsqrtf(var + EPSf);
        #pragma unroll
        for (int j = 0; j < 16; ++j) {
            int col = s * 16 + j;
            float a = (vals[j] - mu) * rs * g[col] + bt[col];
            row[col] = a > 0.f ? a : 0.f;
        }
    }
    __syncthreads();

    #pragma unroll
    for (int e = 0; e < 16; ++e) acc[e] = 0.f;
    for (int k = 0; k < 128; k += 4) {
        float w0 = W2[(k + 0) * 128 + c], w1 = W2[(k + 1) * 128 + c];
        float w2 = W2[(k + 2) * 128 + c], w3 = W2[(k + 3) * 128 + c];
        #pragma unroll
        for (int e = 0; e < 16; ++e) {
            float4 a = *(const float4*)(sY + (eg + e) * 128 + k);
            acc[e] += a.x * w0 + a.y * w1 + a.z * w2 + a.w * w3;
        }
    }
    {
        float bb = b2[c];
        #pragma unroll
        for (int e = 0; e < 16; ++e) {
            int node = n0 + eg + e;
            if (node < NN) q[node * 128 + c] = acc[e] + bb;
        }
    }
}

// ------- per-edge MFMA kernel (transposed C): kv build, L1, in-reg LN, L2k+logits+exp, L2v -------
__global__ __launch_bounds__(256, 3) void k_edge(
    const float* __restrict__ x, const unsigned short* __restrict__ h_bf,
    const float* __restrict__ ea, const int* __restrict__ ei,
    const unsigned short* __restrict__ Wt1,
    const float* __restrict__ kb1, const float* __restrict__ vb1,
    const float* __restrict__ kg, const float* __restrict__ kbt,
    const float* __restrict__ vg, const float* __restrict__ vbt,
    const unsigned short* __restrict__ kW2t, const float* __restrict__ kb2,
    const unsigned short* __restrict__ vW2t, const float* __restrict__ vb2,
    const float* __restrict__ q,
    float* __restrict__ exbuf, float* __restrict__ denom,
    float* __restrict__ vout, float* __restrict__ relx)
{
    // phase A: kv tile [64 rows][384 halves] (48 16B-chunks/row, xor-swizzled by row&7)
    // phase B: Y tile  [64 rows][256 halves] (32 chunks/row, same swizzle) overlaid at offset 0
    __shared__ __align__(16) unsigned short sR[64 * 384];
    __shared__ float2 sStats[4 * 64];
    __shared__ float sEA[64 * 4];
    __shared__ float sDist[64];
    __shared__ int   sSrc[64], sDst[64];

    const int tid  = threadIdx.x;
    const int e0   = blockIdx.x * 64;
    const int lane = tid & 63;
    const int wv   = tid >> 6;
    const int rA   = lane & 15;
    const int kq   = lane >> 4;

    if (tid < 64) {
        int e = e0 + tid;
        int s = ei[e], d = ei[EE + e];
        sSrc[tid] = s; sDst[tid] = d;
        float rx = x[d*3+0] - x[s*3+0];
        float ry = x[d*3+1] - x[s*3+1];
        float rz = x[d*3+2] - x[s*3+2];
        relx[e*3+0] = rx; relx[e*3+1] = ry; relx[e*3+2] = rz;
        sDist[tid] = sqrtf(rx*rx + ry*ry + rz*rz);
        sEA[tid*4+0] = ea[e*4+0]; sEA[tid*4+1] = ea[e*4+1];
        sEA[tid*4+2] = ea[e*4+2]; sEA[tid*4+3] = ea[e*4+3];
    }
    __syncthreads();

    // h gather: chunks 0..31 (k' 0..255); chunk<16 -> h[dst], else h[src]
    #pragma unroll
    for (int it = 0; it < 8; ++it) {
        int p = tid + it * 256;
        int r = p >> 5, c = p & 31;
        int node = (c < 16) ? sDst[r] : sSrc[r];
        int cc = c & 15;
        uint4 v = *(const uint4*)(h_bf + node * 128 + cc * 8);
        *(uint4*)(&sR[r * 384 + ((c ^ (r & 7)) << 3)]) = v;
    }
    // ea + dist_feat + zero pad: k' 256..383
    const float step  = 10.0f / 19.0f;
    const float coeff = -0.5f / (step * step);
    #pragma unroll
    for (int it = 0; it < 32; ++it) {
        int p = tid + it * 256;
        int r = p >> 7, i = p & 127;
        int k = 256 + i;
        float val;
        if (i < 4) val = sEA[r*4 + i];
        else if (i < 84) {
            int f = (i - 4) / 20, gg = (i - 4) % 20;
            float dd = sDist[r] - (float)gg * step;
            val = sEA[r*4 + f] * __expf(coeff * dd * dd);
        } else val = 0.f;
        int c = k >> 3;
        sR[r * 384 + ((c ^ (r & 7)) << 3) + (k & 7)] = f2bf(val);
    }
    __syncthreads();

    // ---- layer 1 (transposed): C[n][e]; wave wv owns cols n0..n0+63 ----
    const int n0 = wv * 64;
    f32x4 zf = {0.f, 0.f, 0.f, 0.f};
    f32x4 acc[4][4];   // [nf][ef]
    #pragma unroll
    for (int nf = 0; nf < 4; ++nf)
        #pragma unroll
        for (int ef = 0; ef < 4; ++ef) acc[nf][ef] = zf;

    for (int k0 = 0; k0 < 352; k0 += 32) {
        int cbase = (k0 >> 3) + kq;
        short8 wfr[4], kv[4];
        #pragma unroll
        for (int nf = 0; nf < 4; ++nf)
            wfr[nf] = *(const short8*)(Wt1 + (n0 + nf * 16 + rA) * 352 + k0 + kq * 8);
        #pragma unroll
        for (int ef = 0; ef < 4; ++ef) {
            int r = ef * 16 + rA;
            kv[ef] = *(const short8*)(&sR[r * 384 + ((cbase ^ (r & 7)) << 3)]);
        }
        #pragma unroll
        for (int nf = 0; nf < 4; ++nf)
            #pragma unroll
            for (int ef = 0; ef < 4; ++ef)
                acc[nf][ef] = __builtin_amdgcn_mfma_f32_16x16x32_bf16(wfr[nf], kv[ef], acc[nf][ef], 0, 0, 0);
    }

    // ---- bias add (before LN stats) ----
    {
        const float* bsrc = (wv < 2) ? kb1 : vb1;
        int cb = (wv & 1) * 64;
        #pragma unroll
        for (int nf = 0; nf < 4; ++nf) {
            f32x4 bb = *(const f32x4*)(bsrc + cb + nf * 16 + kq * 4);
            #pragma unroll
            for (int ef = 0; ef < 4; ++ef)
                #pragma unroll
                for (int j = 0; j < 4; ++j) acc[nf][ef][j] += bb[j];
        }
    }

    // ---- in-register LN stats: per edge (lane holds 16 cols of edge ef*16+rA) ----
    float sm[4], sq2[4];
    #pragma unroll
    for (int ef = 0; ef < 4; ++ef) {
        float s = 0.f, s2 = 0.f;
        #pragma unroll
        for (int nf = 0; nf < 4; ++nf)
            #pragma unroll
            for (int j = 0; j < 4; ++j) { float v = acc[nf][ef][j]; s += v; s2 += v * v; }
        sm[ef] = s; sq2[ef] = s2;
    }
    #pragma unroll
    for (int ef = 0; ef < 4; ++ef) {
        sm[ef]  += __shfl_xor(sm[ef], 16, 64);  sm[ef]  += __shfl_xor(sm[ef], 32, 64);
        sq2[ef] += __shfl_xor(sq2[ef], 16, 64); sq2[ef] += __shfl_xor(sq2[ef], 32, 64);
    }
    if (kq == 0) {
        #pragma unroll
        for (int ef = 0; ef < 4; ++ef)
            sStats[wv * 64 + ef * 16 + rA] = make_float2(sm[ef], sq2[ef]);
    }
    __syncthreads();   // stats ready; also: all waves done reading kv region

    // ---- normalize + ReLU + pack -> Y LDS (bf16, b64 writes) ----
    {
        const float* gp = (wv < 2) ? kg : vg;
        const float* bp = (wv < 2) ? kbt : vbt;
        f32x4 g4[4], b4[4];
        #pragma unroll
        for (int nf = 0; nf < 4; ++nf) {
            int cl = (wv & 1) * 64 + nf * 16 + kq * 4;
            g4[nf] = *(const f32x4*)(gp + cl);
            b4[nf] = *(const f32x4*)(bp + cl);
        }
        #pragma unroll
        for (int ef = 0; ef < 4; ++ef) {
            int e = ef * 16 + rA;
            float2 po = sStats[(wv ^ 1) * 64 + e];
            float mu  = (sm[ef] + po.x) * (1.f / 128.f);
            float var = (sq2[ef] + po.y) * (1.f / 128.f) - mu * mu;
            float rs  = rsqrtf(var + EPSf);
            #pragma unroll
            for (int nf = 0; nf < 4; ++nf) {
                float y[4];
                #pragma unroll
                for (int j = 0; j < 4; ++j) {
                    float f = (acc[nf][ef][j] - mu) * rs * g4[nf][j] + b4[nf][j];
                    y[j] = f > 0.f ? f : 0.f;
                }
                int col = n0 + nf * 16 + kq * 4;
                int ch = col >> 3;
                uint2 pw; pw.x = pk2(y[0], y[1]); pw.y = pk2(y[2], y[3]);
                *(uint2*)(&sR[e * 256 + ((ch ^ (e & 7)) << 3) + (col & 7)]) = pw;
            }
        }
    }
    __syncthreads();

    // ---- layer 2 (k) transposed + fused logits + exp + denom atomic ----
    {
        const int n0k = wv * 32;
        f32x4 a2[2][4];
        #pragma unroll
        for (int nf2 = 0; nf2 < 2; ++nf2)
            #pragma unroll
            for (int ef = 0; ef < 4; ++ef) a2[nf2][ef] = zf;
        for (int k0 = 0; k0 < 128; k0 += 32) {
            int cbase = (k0 >> 3) + kq;
            short8 wf2[2], yf[4];
            #pragma unroll
            for (int nf2 = 0; nf2 < 2; ++nf2)
                wf2[nf2] = *(const short8*)(kW2t + (n0k + nf2 * 16 + rA) * 128 + k0 + kq * 8);
            #pragma unroll
            for (int ef = 0; ef < 4; ++ef) {
                int r = ef * 16 + rA;
                yf[ef] = *(const short8*)(&sR[r * 256 + ((cbase ^ (r & 7)) << 3)]);
            }
            #pragma unroll
            for (int nf2 = 0; nf2 < 2; ++nf2)
                #pragma unroll
                for (int ef = 0; ef < 4; ++ef)
                    a2[nf2][ef] = __builtin_amdgcn_mfma_f32_16x16x32_bf16(wf2[nf2], yf[ef], a2[nf2][ef], 0, 0, 0);
        }
        f32x4 bb2[2];
        bb2[0] = *(const f32x4*)(kb2 + n0k + kq * 4);
        bb2[1] = *(const f32x4*)(kb2 + n0k + 16 + kq * 4);
        int dloc[4];
        #pragma unroll
        for (int ef = 0; ef < 4; ++ef) dloc[ef] = sDst[ef * 16 + rA];

        float ps[2][4];
        #pragma unroll
        for (int nf2 = 0; nf2 < 2; ++nf2)
            #pragma unroll
            for (int ef = 0; ef < 4; ++ef) {
                const float* qn = q + dloc[ef] * 128 + n0k + nf2 * 16 + kq * 4;
                f32x4 qv = *(const f32x4*)qn;
                float s = 0.f;
                #pragma unroll
                for (int j = 0; j < 4; ++j) s += qv[j] * (a2[nf2][ef][j] + bb2[nf2][j]);
                ps[nf2][ef] = s;
            }
        #pragma unroll
        for (int nf2 = 0; nf2 < 2; ++nf2)
            #pragma unroll
            for (int ef = 0; ef < 4; ++ef)
                ps[nf2][ef] += __shfl_xor(ps[nf2][ef], 16, 64);

        int h_base = wv * 4 + (kq >> 1);
        #pragma unroll
        for (int nf2 = 0; nf2 < 2; ++nf2)
            #pragma unroll
            for (int ef = 0; ef < 4; ++ef) {
                bool act = ((kq & 1) == 0) ? (ef < 2) : (ef >= 2);
                if (act) {
                    int e = ef * 16 + rA;
                    int hh = h_base + nf2 * 2;
                    float ex = __expf(ps[nf2][ef] * 0.35355339059327373f);
                    exbuf[(e0 + e) * 16 + hh] = ex;
                    atomicAdd(denom + dloc[ef] * 16 + hh, ex);
                }
            }
    }

    // ---- layer 2 (v) transposed: wave wv owns edges wv*16..wv*16+15; float4 out ----
    {
        f32x4 av = zf;
        int r = wv * 16 + rA;
        for (int k0 = 0; k0 < 128; k0 += 32) {
            int cbase = 16 + (k0 >> 3) + kq;
            short8 yv  = *(const short8*)(&sR[r * 256 + ((cbase ^ (r & 7)) << 3)]);
            short8 wfv = *(const short8*)(vW2t + rA * 128 + k0 + kq * 8);
            av = __builtin_amdgcn_mfma_f32_16x16x32_bf16(wfv, yv, av, 0, 0, 0);
        }
        f32x4 bv = *(const f32x4*)(vb2 + kq * 4);
        f32x4 vo;
        #pragma unroll
        for (int j = 0; j < 4; ++j) vo[j] = av[j] + bv[j];
        *(f32x4*)(vout + (e0 + wv * 16 + rA) * 16 + kq * 4) = vo;
    }
}

// ---------------------- scatter: alpha * v * rel_x -> out ----------------------
__global__ void k_scatter(const int* __restrict__ ei, const float* __restrict__ exs,
                          const float* __restrict__ denom, const float* __restrict__ vout,
                          const float* __restrict__ relx, float* __restrict__ out) {
    int e = blockIdx.x * 256 + threadIdx.x;
    int d = ei[EE + e];
    const float* ex = exs + e * 16;
    const float* dn = denom + d * 16;
    const float* vv = vout + e * 16;
    float s = 0.f;
    #pragma unroll
    for (int hh = 0; hh < 16; ++hh) s += ex[hh] / dn[hh] * vv[hh];
    s *= (1.0f / 16.0f);
    atomicAdd(&out[d * 3 + 0], s * relx[e * 3 + 0]);
    atomicAdd(&out[d * 3 + 1], s * relx[e * 3 + 1]);
    atomicAdd(&out[d * 3 + 2], s * relx[e * 3 + 2]);
}

extern "C" void kernel_launch(void* const* d_in, const int* in_sizes, int n_in,
                              void* d_out, int out_size, void* d_ws, size_t ws_size,
                              hipStream_t stream) {
    const float* x   = (const float*)d_in[0];
    const float* h   = (const float*)d_in[1];
    const float* ea  = (const float*)d_in[2];
    const int*   ei  = (const int*)d_in[4];
    const float* kW1 = (const float*)d_in[5];
    const float* kb1 = (const float*)d_in[6];
    const float* kg  = (const float*)d_in[7];
    const float* kbt = (const float*)d_in[8];
    const float* kW2 = (const float*)d_in[9];
    const float* kb2 = (const float*)d_in[10];
    const float* vW1 = (const float*)d_in[11];
    const float* vb1 = (const float*)d_in[12];
    const float* vg  = (const float*)d_in[13];
    const float* vbt = (const float*)d_in[14];
    const float* vW2 = (const float*)d_in[15];
    const float* vb2 = (const float*)d_in[16];
    const float* qW1 = (const float*)d_in[17];
    const float* qb1 = (const float*)d_in[18];
    const float* qg  = (const float*)d_in[19];
    const float* qbt = (const float*)d_in[20];
    const float* qW2 = (const float*)d_in[21];
    const float* qb2 = (const float*)d_in[22];

    float* ws = (float*)d_ws;
    float*    qbuf   = ws;                           // N*128
    float*    exbuf  = ws + 1280000;                 // E*16
    float*    vbuf   = ws + 6400000;                 // E*16
    float*    relx   = ws + 11520000;                // E*3
    float*    denom  = ws + 12480000;                // N*16
    unsigned short* h_bf = (unsigned short*)(ws + 12640000);   // N*128 halves
    unsigned short* Wt1  = (unsigned short*)(ws + 13280000);   // 256*352 halves
    unsigned short* kW2t = (unsigned short*)(ws + 13325056);   // 128*128 halves
    unsigned short* vW2t = (unsigned short*)(ws + 13333248);   // 16*128 halves
    float* out = (float*)d_out;

    hipLaunchKernelGGL(k_init, dim3(625), dim3(256), 0, stream, denom, out);
    hipLaunchKernelGGL(k_prep, dim3(5424), dim3(256), 0, stream,
                       h, kW1, vW1, kW2, vW2, h_bf, Wt1, kW2t, vW2t);
    hipLaunchKernelGGL(k_qmlp, dim3(313), dim3(256), 0, stream,
                       h, qW1, qb1, qg, qbt, qW2, qb2, qbuf);
    hipLaunchKernelGGL(k_edge, dim3(5000), dim3(256), 0, stream,
                       x, h_bf, ea, ei, Wt1,
                       kb1, vb1, kg, kbt, vg, vbt,
                       kW2t, kb2, vW2t, vb2,
                       qbuf, exbuf, denom, vbuf, relx);
    hipLaunchKernelGGL(k_scatter, dim3(1250), dim3(256), 0, stream,
                       ei, exbuf, denom, vbuf, relx, out);
}

// Round 4
// 290.213 us; speedup vs baseline: 1.1476x; 1.1476x over previous
//
#include <hip/hip_runtime.h>
#include <math.h>

typedef __attribute__((ext_vector_type(8))) short short8;
typedef __attribute__((ext_vector_type(4))) float f32x4;

#define NN 10000
#define EE 320000
#define NHEAD 16
#define EPSf 1e-5f

// ---------- bf16 helpers ----------
__device__ __forceinline__ unsigned short f2bf(float f) {
    union { float f; unsigned u; } v; v.f = f;
    unsigned u = v.u;
    u += 0x7fffu + ((u >> 16) & 1u);   // RNE
    return (unsigned short)(u >> 16);
}
__device__ __forceinline__ unsigned pk2(float a, float b) {
    return ((unsigned)f2bf(b) << 16) | (unsigned)f2bf(a);
}

// ---------------------- CSR build: zero, hist, scan, place ----------------------
__global__ void k_zero(int* __restrict__ cnt) {
    int i = blockIdx.x * 256 + threadIdx.x;
    if (i < NN) cnt[i] = 0;
}

__global__ void k_hist(const int* __restrict__ ei, int* __restrict__ cnt) {
    int e = blockIdx.x * 256 + threadIdx.x;
    if (e < EE) atomicAdd(&cnt[ei[EE + e]], 1);
}

__global__ __launch_bounds__(1024) void k_scan(const int* __restrict__ cnt,
                                               int* __restrict__ base, int* __restrict__ cnt2) {
    __shared__ int part[1024];
    const int t = threadIdx.x;
    int loc[10];
    int s = 0;
    #pragma unroll
    for (int i = 0; i < 10; ++i) {
        int idx = t * 10 + i;
        loc[i] = (idx < NN) ? cnt[idx] : 0;
        s += loc[i];
    }
    part[t] = s;
    __syncthreads();
    for (int off = 1; off < 1024; off <<= 1) {
        int v = (t >= off) ? part[t - off] : 0;
        __syncthreads();
        part[t] += v;
        __syncthreads();
    }
    int run = part[t] - s;   // exclusive prefix
    #pragma unroll
    for (int i = 0; i < 10; ++i) {
        int idx = t * 10 + i;
        if (idx < NN) { base[idx] = run; cnt2[idx] = run; run += loc[i]; }
    }
    if (t == 1023) base[NN] = part[1023];
}

__global__ void k_place(const int* __restrict__ ei, int* __restrict__ cnt2,
                        int* __restrict__ perm) {
    int e = blockIdx.x * 256 + threadIdx.x;
    if (e < EE) {
        int slot = atomicAdd(&cnt2[ei[EE + e]], 1);
        perm[slot] = e;
    }
}

// ------------- prep: bf16-convert h; transpose+bf16+K-permute weights -------------
// kv layout (k'): [0..127]=h_dst, [128..255]=h_src, [256..259]=ea, [260..339]=dist, [340..383]=0
__global__ void k_prep(const float* __restrict__ h,
                       const float* __restrict__ kW1, const float* __restrict__ vW1,
                       const float* __restrict__ kW2, const float* __restrict__ vW2,
                       unsigned short* __restrict__ h_bf, unsigned short* __restrict__ Wt1,
                       unsigned short* __restrict__ kW2t, unsigned short* __restrict__ vW2t) {
    int i = blockIdx.x * 256 + threadIdx.x;
    if (i < NN * 128) { h_bf[i] = f2bf(h[i]); return; }
    int j = i - NN * 128;
    if (j < 256 * 352) {
        int n = j / 352, k = j % 352;
        float val = 0.f;
        if (k < 340) {
            int pk;
            if (k < 128)      pk = 84 + k;
            else if (k < 256) pk = 212 + (k - 128);
            else if (k < 260) pk = k - 256;
            else              pk = 4 + (k - 260);
            val = (n < 128) ? kW1[pk * 128 + n] : vW1[pk * 128 + (n - 128)];
        }
        Wt1[j] = f2bf(val); return;
    }
    j -= 256 * 352;
    if (j < 128 * 128) { int n = j >> 7, k = j & 127; kW2t[j] = f2bf(kW2[k * 128 + n]); return; }
    j -= 128 * 128;
    if (j < 16 * 128)  { int n = j >> 7, k = j & 127; vW2t[j] = f2bf(vW2[k * 16 + n]); return; }
}

// ---------------------- q = MLP(h) in f32 (small) ----------------------
__global__ __launch_bounds__(256) void k_qmlp(
    const float* __restrict__ h,
    const float* __restrict__ W1, const float* __restrict__ b1,
    const float* __restrict__ g,  const float* __restrict__ bt,
    const float* __restrict__ W2, const float* __restrict__ b2,
    float* __restrict__ q)
{
    __shared__ float sH[32 * 128];
    __shared__ float sY[32 * 128];
    const int tid = threadIdx.x;
    const int n0 = blockIdx.x * 32;

    #pragma unroll
    for (int j = 0; j < 4; ++j) {
        int p = tid + j * 256;
        int e = p >> 5, i = p & 31;
        int node = n0 + e; if (node >= NN) node = NN - 1;
        float4 v = *(const float4*)(h + node * 128 + i * 4);
        *(float4*)(sH + e * 128 + i * 4) = v;
    }
    __syncthreads();

    const int c  = tid & 127;
    const int eg = (tid >> 7) * 16;
    float acc[16];
    #pragma unroll
    for (int e = 0; e < 16; ++e) acc[e] = 0.f;
    for (int k = 0; k < 128; k += 4) {
        float w0 = W1[(k + 0) * 128 + c], w1 = W1[(k + 1) * 128 + c];
        float w2 = W1[(k + 2) * 128 + c], w3 = W1[(k + 3) * 128 + c];
        #pragma unroll
        for (int e = 0; e < 16; ++e) {
            float4 a = *(const float4*)(sH + (eg + e) * 128 + k);
            acc[e] += a.x * w0 + a.y * w1 + a.z * w2 + a.w * w3;
        }
    }
    {
        float bb = b1[c];
        #pragma unroll
        for (int e = 0; e < 16; ++e) sY[(eg + e) * 128 + c] = acc[e] + bb;
    }
    __syncthreads();

    {
        int r = tid >> 3, s = tid & 7;
        float* row = sY + r * 128;
        float vals[16];
        float sum = 0.f, sq = 0.f;
        #pragma unroll
        for (int j = 0; j < 4; ++j) {
            float4 v = *(float4*)(row + s * 16 + j * 4);
            vals[j*4+0] = v.x; vals[j*4+1] = v.y; vals[j*4+2] = v.z; vals[j*4+3] = v.w;
        }
        #pragma unroll
        for (int j = 0; j < 16; ++j) { sum += vals[j]; sq += vals[j] * vals[j]; }
        #pragma unroll
        for (int o = 1; o < 8; o <<= 1) { sum += __shfl_xor(sum, o, 64); sq += __shfl_xor(sq, o, 64); }
        float mu = sum * (1.f / 128.f);
        float var = sq * (1.f / 128.f) - mu * mu;
        float rs = rsqrtf(var + EPSf);
        #pragma unroll
        for (int j = 0; j < 16; ++j) {
            int col = s * 16 + j;
            float a = (vals[j] - mu) * rs * g[col] + bt[col];
            row[col] = a > 0.f ? a : 0.f;
        }
    }
    __syncthreads();

    #pragma unroll
    for (int e = 0; e < 16; ++e) acc[e] = 0.f;
    for (int k = 0; k < 128; k += 4) {
        float w0 = W2[(k + 0) * 128 + c], w1 = W2[(k + 1) * 128 + c];
        float w2 = W2[(k + 2) * 128 + c], w3 = W2[(k + 3) * 128 + c];
        #pragma unroll
        for (int e = 0; e < 16; ++e) {
            float4 a = *(const float4*)(sY + (eg + e) * 128 + k);
            acc[e] += a.x * w0 + a.y * w1 + a.z * w2 + a.w * w3;
        }
    }
    {
        float bb = b2[c];
        #pragma unroll
        for (int e = 0; e < 16; ++e) {
            int node = n0 + eg + e;
            if (node < NN) q[node * 128 + c] = acc[e] + bb;
        }
    }
}

// ------- per-slot MFMA kernel (CSR-permuted edges, transposed C) -------
__global__ __launch_bounds__(256, 3) void k_edge(
    const float* __restrict__ x, const unsigned short* __restrict__ h_bf,
    const float* __restrict__ ea, const int* __restrict__ ei,
    const int* __restrict__ perm,
    const unsigned short* __restrict__ Wt1,
    const float* __restrict__ kb1, const float* __restrict__ vb1,
    const float* __restrict__ kg, const float* __restrict__ kbt,
    const float* __restrict__ vg, const float* __restrict__ vbt,
    const unsigned short* __restrict__ kW2t, const float* __restrict__ kb2,
    const unsigned short* __restrict__ vW2t, const float* __restrict__ vb2,
    const float* __restrict__ q,
    float* __restrict__ exbuf, float* __restrict__ vout, float* __restrict__ relx)
{
    // phase A: kv tile [64 rows][384 halves] (48 16B-chunks/row, xor-swizzled by row&7)
    // phase B: Y tile  [64 rows][256 halves] (32 chunks/row, same swizzle) overlaid at offset 0
    __shared__ __align__(16) unsigned short sR[64 * 384];
    __shared__ float2 sStats[4 * 64];
    __shared__ float sEA[64 * 4];
    __shared__ float sDist[64];
    __shared__ int   sSrc[64], sDst[64];

    const int tid  = threadIdx.x;
    const int e0   = blockIdx.x * 64;
    const int lane = tid & 63;
    const int wv   = tid >> 6;
    const int rA   = lane & 15;
    const int kq   = lane >> 4;

    if (tid < 64) {
        int slot = e0 + tid;
        int e = perm[slot];
        int s = ei[e], d = ei[EE + e];
        sSrc[tid] = s; sDst[tid] = d;
        float rx = x[d*3+0] - x[s*3+0];
        float ry = x[d*3+1] - x[s*3+1];
        float rz = x[d*3+2] - x[s*3+2];
        relx[slot*3+0] = rx; relx[slot*3+1] = ry; relx[slot*3+2] = rz;
        sDist[tid] = sqrtf(rx*rx + ry*ry + rz*rz);
        float4 eav = *(const float4*)(ea + e * 4);
        sEA[tid*4+0] = eav.x; sEA[tid*4+1] = eav.y;
        sEA[tid*4+2] = eav.z; sEA[tid*4+3] = eav.w;
    }
    __syncthreads();

    // h gather: chunks 0..31 (k' 0..255); chunk<16 -> h[dst], else h[src]
    #pragma unroll
    for (int it = 0; it < 8; ++it) {
        int p = tid + it * 256;
        int r = p >> 5, c = p & 31;
        int node = (c < 16) ? sDst[r] : sSrc[r];
        int cc = c & 15;
        uint4 v = *(const uint4*)(h_bf + node * 128 + cc * 8);
        *(uint4*)(&sR[r * 384 + ((c ^ (r & 7)) << 3)]) = v;
    }
    // ea + dist_feat + zero pad: k' 256..383
    const float step  = 10.0f / 19.0f;
    const float coeff = -0.5f / (step * step);
    #pragma unroll
    for (int it = 0; it < 32; ++it) {
        int p = tid + it * 256;
        int r = p >> 7, i = p & 127;
        int k = 256 + i;
        float val;
        if (i < 4) val = sEA[r*4 + i];
        else if (i < 84) {
            int f = (i - 4) / 20, gg = (i - 4) % 20;
            float dd = sDist[r] - (float)gg * step;
            val = sEA[r*4 + f] * __expf(coeff * dd * dd);
        } else val = 0.f;
        int c = k >> 3;
        sR[r * 384 + ((c ^ (r & 7)) << 3) + (k & 7)] = f2bf(val);
    }
    __syncthreads();

    // ---- layer 1 (transposed): C[n][e]; wave wv owns cols n0..n0+63 ----
    const int n0 = wv * 64;
    f32x4 zf = {0.f, 0.f, 0.f, 0.f};
    f32x4 acc[4][4];   // [nf][ef]
    #pragma unroll
    for (int nf = 0; nf < 4; ++nf)
        #pragma unroll
        for (int ef = 0; ef < 4; ++ef) acc[nf][ef] = zf;

    for (int k0 = 0; k0 < 352; k0 += 32) {
        int cbase = (k0 >> 3) + kq;
        short8 wfr[4], kv[4];
        #pragma unroll
        for (int nf = 0; nf < 4; ++nf)
            wfr[nf] = *(const short8*)(Wt1 + (n0 + nf * 16 + rA) * 352 + k0 + kq * 8);
        #pragma unroll
        for (int ef = 0; ef < 4; ++ef) {
            int r = ef * 16 + rA;
            kv[ef] = *(const short8*)(&sR[r * 384 + ((cbase ^ (r & 7)) << 3)]);
        }
        #pragma unroll
        for (int nf = 0; nf < 4; ++nf)
            #pragma unroll
            for (int ef = 0; ef < 4; ++ef)
                acc[nf][ef] = __builtin_amdgcn_mfma_f32_16x16x32_bf16(wfr[nf], kv[ef], acc[nf][ef], 0, 0, 0);
    }

    // ---- bias add (before LN stats) ----
    {
        const float* bsrc = (wv < 2) ? kb1 : vb1;
        int cb = (wv & 1) * 64;
        #pragma unroll
        for (int nf = 0; nf < 4; ++nf) {
            f32x4 bb = *(const f32x4*)(bsrc + cb + nf * 16 + kq * 4);
            #pragma unroll
            for (int ef = 0; ef < 4; ++ef)
                #pragma unroll
                for (int j = 0; j < 4; ++j) acc[nf][ef][j] += bb[j];
        }
    }

    // ---- in-register LN stats ----
    float sm[4], sq2[4];
    #pragma unroll
    for (int ef = 0; ef < 4; ++ef) {
        float s = 0.f, s2 = 0.f;
        #pragma unroll
        for (int nf = 0; nf < 4; ++nf)
            #pragma unroll
            for (int j = 0; j < 4; ++j) { float v = acc[nf][ef][j]; s += v; s2 += v * v; }
        sm[ef] = s; sq2[ef] = s2;
    }
    #pragma unroll
    for (int ef = 0; ef < 4; ++ef) {
        sm[ef]  += __shfl_xor(sm[ef], 16, 64);  sm[ef]  += __shfl_xor(sm[ef], 32, 64);
        sq2[ef] += __shfl_xor(sq2[ef], 16, 64); sq2[ef] += __shfl_xor(sq2[ef], 32, 64);
    }
    if (kq == 0) {
        #pragma unroll
        for (int ef = 0; ef < 4; ++ef)
            sStats[wv * 64 + ef * 16 + rA] = make_float2(sm[ef], sq2[ef]);
    }
    __syncthreads();

    // ---- normalize + ReLU + pack -> Y LDS ----
    {
        const float* gp = (wv < 2) ? kg : vg;
        const float* bp = (wv < 2) ? kbt : vbt;
        f32x4 g4[4], b4[4];
        #pragma unroll
        for (int nf = 0; nf < 4; ++nf) {
            int cl = (wv & 1) * 64 + nf * 16 + kq * 4;
            g4[nf] = *(const f32x4*)(gp + cl);
            b4[nf] = *(const f32x4*)(bp + cl);
        }
        #pragma unroll
        for (int ef = 0; ef < 4; ++ef) {
            int e = ef * 16 + rA;
            float2 po = sStats[(wv ^ 1) * 64 + e];
            float mu  = (sm[ef] + po.x) * (1.f / 128.f);
            float var = (sq2[ef] + po.y) * (1.f / 128.f) - mu * mu;
            float rs  = rsqrtf(var + EPSf);
            #pragma unroll
            for (int nf = 0; nf < 4; ++nf) {
                float y[4];
                #pragma unroll
                for (int j = 0; j < 4; ++j) {
                    float f = (acc[nf][ef][j] - mu) * rs * g4[nf][j] + b4[nf][j];
                    y[j] = f > 0.f ? f : 0.f;
                }
                int col = n0 + nf * 16 + kq * 4;
                int ch = col >> 3;
                uint2 pw; pw.x = pk2(y[0], y[1]); pw.y = pk2(y[2], y[3]);
                *(uint2*)(&sR[e * 256 + ((ch ^ (e & 7)) << 3) + (col & 7)]) = pw;
            }
        }
    }
    __syncthreads();

    // ---- layer 2 (k) transposed + fused logits + exp (no atomics) ----
    {
        const int n0k = wv * 32;
        f32x4 a2[2][4];
        #pragma unroll
        for (int nf2 = 0; nf2 < 2; ++nf2)
            #pragma unroll
            for (int ef = 0; ef < 4; ++ef) a2[nf2][ef] = zf;
        for (int k0 = 0; k0 < 128; k0 += 32) {
            int cbase = (k0 >> 3) + kq;
            short8 wf2[2], yf[4];
            #pragma unroll
            for (int nf2 = 0; nf2 < 2; ++nf2)
                wf2[nf2] = *(const short8*)(kW2t + (n0k + nf2 * 16 + rA) * 128 + k0 + kq * 8);
            #pragma unroll
            for (int ef = 0; ef < 4; ++ef) {
                int r = ef * 16 + rA;
                yf[ef] = *(const short8*)(&sR[r * 256 + ((cbase ^ (r & 7)) << 3)]);
            }
            #pragma unroll
            for (int nf2 = 0; nf2 < 2; ++nf2)
                #pragma unroll
                for (int ef = 0; ef < 4; ++ef)
                    a2[nf2][ef] = __builtin_amdgcn_mfma_f32_16x16x32_bf16(wf2[nf2], yf[ef], a2[nf2][ef], 0, 0, 0);
        }
        f32x4 bb2[2];
        bb2[0] = *(const f32x4*)(kb2 + n0k + kq * 4);
        bb2[1] = *(const f32x4*)(kb2 + n0k + 16 + kq * 4);
        int dloc[4];
        #pragma unroll
        for (int ef = 0; ef < 4; ++ef) dloc[ef] = sDst[ef * 16 + rA];

        float ps[2][4];
        #pragma unroll
        for (int nf2 = 0; nf2 < 2; ++nf2)
            #pragma unroll
            for (int ef = 0; ef < 4; ++ef) {
                const float* qn = q + dloc[ef] * 128 + n0k + nf2 * 16 + kq * 4;
                f32x4 qv = *(const f32x4*)qn;
                float s = 0.f;
                #pragma unroll
                for (int j = 0; j < 4; ++j) s += qv[j] * (a2[nf2][ef][j] + bb2[nf2][j]);
                ps[nf2][ef] = s;
            }
        #pragma unroll
        for (int nf2 = 0; nf2 < 2; ++nf2)
            #pragma unroll
            for (int ef = 0; ef < 4; ++ef)
                ps[nf2][ef] += __shfl_xor(ps[nf2][ef], 16, 64);

        int h_base = wv * 4 + (kq >> 1);
        #pragma unroll
        for (int nf2 = 0; nf2 < 2; ++nf2)
            #pragma unroll
            for (int ef = 0; ef < 4; ++ef) {
                bool act = ((kq & 1) == 0) ? (ef < 2) : (ef >= 2);
                if (act) {
                    int e = ef * 16 + rA;
                    int hh = h_base + nf2 * 2;
                    float ex = __expf(ps[nf2][ef] * 0.35355339059327373f);
                    exbuf[(e0 + e) * 16 + hh] = ex;
                }
            }
    }

    // ---- layer 2 (v) transposed: wave wv owns slots wv*16..wv*16+15; float4 out ----
    {
        f32x4 av = zf;
        int r = wv * 16 + rA;
        for (int k0 = 0; k0 < 128; k0 += 32) {
            int cbase = 16 + (k0 >> 3) + kq;
            short8 yv  = *(const short8*)(&sR[r * 256 + ((cbase ^ (r & 7)) << 3)]);
            short8 wfv = *(const short8*)(vW2t + rA * 128 + k0 + kq * 8);
            av = __builtin_amdgcn_mfma_f32_16x16x32_bf16(wfv, yv, av, 0, 0, 0);
        }
        f32x4 bv = *(const f32x4*)(vb2 + kq * 4);
        f32x4 vo;
        #pragma unroll
        for (int j = 0; j < 4; ++j) vo[j] = av[j] + bv[j];
        *(f32x4*)(vout + (e0 + wv * 16 + rA) * 16 + kq * 4) = vo;
    }
}

// ---------------------- per-node softmax + output (no atomics) ----------------------
__global__ __launch_bounds__(256) void k_out(
    const int* __restrict__ base, const float* __restrict__ exbuf,
    const float* __restrict__ vbuf, const float* __restrict__ relx,
    float* __restrict__ out)
{
    const int lane = threadIdx.x & 63;
    const int wv   = threadIdx.x >> 6;
    const int n    = blockIdx.x * 4 + wv;
    if (n >= NN) return;
    const int s0 = base[n], s1 = base[n + 1];
    const int sg = lane >> 4;      // slot subgroup 0..3
    const int hh = lane & 15;

    // pass 1: denom per head
    float dsum = 0.f;
    for (int s = s0 + sg; s < s1; s += 4) dsum += exbuf[s * 16 + hh];
    dsum += __shfl_xor(dsum, 16, 64);
    dsum += __shfl_xor(dsum, 32, 64);
    float inv = (dsum > 0.f) ? (1.f / dsum) : 0.f;

    // pass 2: sum over slots of (1/16) * sum_h alpha*v * relx
    float ax = 0.f, ay = 0.f, az = 0.f;
    for (int s = s0 + sg; s < s1; s += 4) {
        float al = exbuf[s * 16 + hh] * inv * vbuf[s * 16 + hh];
        al += __shfl_xor(al, 1, 64);
        al += __shfl_xor(al, 2, 64);
        al += __shfl_xor(al, 4, 64);
        al += __shfl_xor(al, 8, 64);
        float m = al * (1.f / 16.f);
        ax += m * relx[s * 3 + 0];
        ay += m * relx[s * 3 + 1];
        az += m * relx[s * 3 + 2];
    }
    ax += __shfl_xor(ax, 16, 64); ax += __shfl_xor(ax, 32, 64);
    ay += __shfl_xor(ay, 16, 64); ay += __shfl_xor(ay, 32, 64);
    az += __shfl_xor(az, 16, 64); az += __shfl_xor(az, 32, 64);
    if (lane == 0) {
        out[n * 3 + 0] = ax;
        out[n * 3 + 1] = ay;
        out[n * 3 + 2] = az;
    }
}

extern "C" void kernel_launch(void* const* d_in, const int* in_sizes, int n_in,
                              void* d_out, int out_size, void* d_ws, size_t ws_size,
                              hipStream_t stream) {
    const float* x   = (const float*)d_in[0];
    const float* h   = (const float*)d_in[1];
    const float* ea  = (const float*)d_in[2];
    const int*   ei  = (const int*)d_in[4];
    const float* kW1 = (const float*)d_in[5];
    const float* kb1 = (const float*)d_in[6];
    const float* kg  = (const float*)d_in[7];
    const float* kbt = (const float*)d_in[8];
    const float* kW2 = (const float*)d_in[9];
    const float* kb2 = (const float*)d_in[10];
    const float* vW1 = (const float*)d_in[11];
    const float* vb1 = (const float*)d_in[12];
    const float* vg  = (const float*)d_in[13];
    const float* vbt = (const float*)d_in[14];
    const float* vW2 = (const float*)d_in[15];
    const float* vb2 = (const float*)d_in[16];
    const float* qW1 = (const float*)d_in[17];
    const float* qb1 = (const float*)d_in[18];
    const float* qg  = (const float*)d_in[19];
    const float* qbt = (const float*)d_in[20];
    const float* qW2 = (const float*)d_in[21];
    const float* qb2 = (const float*)d_in[22];

    float* ws = (float*)d_ws;
    float* qbuf  = ws;                          // N*128   = 1,280,000 w
    float* exbuf = ws + 1280000;                // E*16    = 5,120,000 w
    float* vbuf  = ws + 6400000;                // E*16    = 5,120,000 w
    float* relx  = ws + 11520000;               // E*3     =   960,000 w
    unsigned short* h_bf = (unsigned short*)(ws + 12480000);   // N*128 halves (640,000 w)
    unsigned short* Wt1  = (unsigned short*)(ws + 13120000);   // 256*352 halves (45,056 w)
    unsigned short* kW2t = (unsigned short*)(ws + 13165056);   // 128*128 halves (8,192 w)
    unsigned short* vW2t = (unsigned short*)(ws + 13173248);   // 16*128 halves (1,024 w)
    int* cnt  = (int*)(ws + 13174272);          // N
    int* base = (int*)(ws + 13184272);          // N+1
    int* cnt2 = (int*)(ws + 13194273);          // N
    int* perm = (int*)(ws + 13204273);          // E
    float* out = (float*)d_out;

    hipLaunchKernelGGL(k_zero,  dim3(40),   dim3(256),  0, stream, cnt);
    hipLaunchKernelGGL(k_hist,  dim3(1250), dim3(256),  0, stream, ei, cnt);
    hipLaunchKernelGGL(k_scan,  dim3(1),    dim3(1024), 0, stream, cnt, base, cnt2);
    hipLaunchKernelGGL(k_place, dim3(1250), dim3(256),  0, stream, ei, cnt2, perm);
    hipLaunchKernelGGL(k_prep,  dim3(5424), dim3(256),  0, stream,
                       h, kW1, vW1, kW2, vW2, h_bf, Wt1, kW2t, vW2t);
    hipLaunchKernelGGL(k_qmlp,  dim3(313),  dim3(256),  0, stream,
                       h, qW1, qb1, qg, qbt, qW2, qb2, qbuf);
    hipLaunchKernelGGL(k_edge,  dim3(5000), dim3(256),  0, stream,
                       x, h_bf, ea, ei, perm, Wt1,
                       kb1, vb1, kg, kbt, vg, vbt,
                       kW2t, kb2, vW2t, vb2,
                       qbuf, exbuf, vbuf, relx);
    hipLaunchKernelGGL(k_out,   dim3(2500), dim3(256),  0, stream,
                       base, exbuf, vbuf, relx, out);
}

// Round 5
// 284.962 us; speedup vs baseline: 1.1688x; 1.0184x over previous
//
#include <hip/hip_runtime.h>
#include <math.h>

typedef __attribute__((ext_vector_type(8))) short short8;
typedef __attribute__((ext_vector_type(4))) float f32x4;

#define NN 10000
#define EE 320000
#define NHEAD 16
#define EPSf 1e-5f

// ---------- bf16 helpers ----------
__device__ __forceinline__ unsigned short f2bf(float f) {
    union { float f; unsigned u; } v; v.f = f;
    unsigned u = v.u;
    u += 0x7fffu + ((u >> 16) & 1u);   // RNE
    return (unsigned short)(u >> 16);
}
__device__ __forceinline__ unsigned pk2(float a, float b) {
    return ((unsigned)f2bf(b) << 16) | (unsigned)f2bf(a);
}

// ---------------------- init: cnt/0, D/0, P/0 ----------------------
__global__ void k_init0(int* __restrict__ cnt, float* __restrict__ Dg,
                        float* __restrict__ Pg) {
    int i = blockIdx.x * 256 + threadIdx.x;
    if (i < NN) cnt[i] = 0;
    if (i < NN * 16) Dg[i] = 0.f;
    if (i < NN * 48) Pg[i] = 0.f;
}

__global__ void k_hist(const int* __restrict__ ei, int* __restrict__ cnt) {
    int e = blockIdx.x * 256 + threadIdx.x;
    if (e < EE) atomicAdd(&cnt[ei[EE + e]], 1);
}

__global__ __launch_bounds__(1024) void k_scan(const int* __restrict__ cnt,
                                               int* __restrict__ base, int* __restrict__ cnt2) {
    __shared__ int part[1024];
    const int t = threadIdx.x;
    int loc[10];
    int s = 0;
    #pragma unroll
    for (int i = 0; i < 10; ++i) {
        int idx = t * 10 + i;
        loc[i] = (idx < NN) ? cnt[idx] : 0;
        s += loc[i];
    }
    part[t] = s;
    __syncthreads();
    for (int off = 1; off < 1024; off <<= 1) {
        int v = (t >= off) ? part[t - off] : 0;
        __syncthreads();
        part[t] += v;
        __syncthreads();
    }
    int run = part[t] - s;   // exclusive prefix
    #pragma unroll
    for (int i = 0; i < 10; ++i) {
        int idx = t * 10 + i;
        if (idx < NN) { base[idx] = run; cnt2[idx] = run; run += loc[i]; }
    }
    if (t == 1023) base[NN] = part[1023];
}

__global__ void k_place(const int* __restrict__ ei, int* __restrict__ cnt2,
                        int* __restrict__ perm) {
    int e = blockIdx.x * 256 + threadIdx.x;
    if (e < EE) {
        int slot = atomicAdd(&cnt2[ei[EE + e]], 1);
        perm[slot] = e;
    }
}

// ------------- prep: bf16-convert h; transpose+bf16+K-permute weights -------------
// kv layout (k'): [0..127]=h_dst, [128..255]=h_src, [256..259]=ea, [260..339]=dist, [340..383]=0
__global__ void k_prep(const float* __restrict__ h,
                       const float* __restrict__ kW1, const float* __restrict__ vW1,
                       const float* __restrict__ kW2, const float* __restrict__ vW2,
                       unsigned short* __restrict__ h_bf, unsigned short* __restrict__ Wt1,
                       unsigned short* __restrict__ kW2t, unsigned short* __restrict__ vW2t) {
    int i = blockIdx.x * 256 + threadIdx.x;
    if (i < NN * 128) { h_bf[i] = f2bf(h[i]); return; }
    int j = i - NN * 128;
    if (j < 256 * 352) {
        int n = j / 352, k = j % 352;
        float val = 0.f;
        if (k < 340) {
            int pk;
            if (k < 128)      pk = 84 + k;
            else if (k < 256) pk = 212 + (k - 128);
            else if (k < 260) pk = k - 256;
            else              pk = 4 + (k - 260);
            val = (n < 128) ? kW1[pk * 128 + n] : vW1[pk * 128 + (n - 128)];
        }
        Wt1[j] = f2bf(val); return;
    }
    j -= 256 * 352;
    if (j < 128 * 128) { int n = j >> 7, k = j & 127; kW2t[j] = f2bf(kW2[k * 128 + n]); return; }
    j -= 128 * 128;
    if (j < 16 * 128)  { int n = j >> 7, k = j & 127; vW2t[j] = f2bf(vW2[k * 16 + n]); return; }
}

// ---------------------- q = MLP(h) in f32 (small) ----------------------
__global__ __launch_bounds__(256) void k_qmlp(
    const float* __restrict__ h,
    const float* __restrict__ W1, const float* __restrict__ b1,
    const float* __restrict__ g,  const float* __restrict__ bt,
    const float* __restrict__ W2, const float* __restrict__ b2,
    float* __restrict__ q)
{
    __shared__ float sH[32 * 128];
    __shared__ float sY[32 * 128];
    const int tid = threadIdx.x;
    const int n0 = blockIdx.x * 32;

    #pragma unroll
    for (int j = 0; j < 4; ++j) {
        int p = tid + j * 256;
        int e = p >> 5, i = p & 31;
        int node = n0 + e; if (node >= NN) node = NN - 1;
        float4 v = *(const float4*)(h + node * 128 + i * 4);
        *(float4*)(sH + e * 128 + i * 4) = v;
    }
    __syncthreads();

    const int c  = tid & 127;
    const int eg = (tid >> 7) * 16;
    float acc[16];
    #pragma unroll
    for (int e = 0; e < 16; ++e) acc[e] = 0.f;
    for (int k = 0; k < 128; k += 4) {
        float w0 = W1[(k + 0) * 128 + c], w1 = W1[(k + 1) * 128 + c];
        float w2 = W1[(k + 2) * 128 + c], w3 = W1[(k + 3) * 128 + c];
        #pragma unroll
        for (int e = 0; e < 16; ++e) {
            float4 a = *(const float4*)(sH + (eg + e) * 128 + k);
            acc[e] += a.x * w0 + a.y * w1 + a.z * w2 + a.w * w3;
        }
    }
    {
        float bb = b1[c];
        #pragma unroll
        for (int e = 0; e < 16; ++e) sY[(eg + e) * 128 + c] = acc[e] + bb;
    }
    __syncthreads();

    {
        int r = tid >> 3, s = tid & 7;
        float* row = sY + r * 128;
        float vals[16];
        float sum = 0.f, sq = 0.f;
        #pragma unroll
        for (int j = 0; j < 4; ++j) {
            float4 v = *(float4*)(row + s * 16 + j * 4);
            vals[j*4+0] = v.x; vals[j*4+1] = v.y; vals[j*4+2] = v.z; vals[j*4+3] = v.w;
        }
        #pragma unroll
        for (int j = 0; j < 16; ++j) { sum += vals[j]; sq += vals[j] * vals[j]; }
        #pragma unroll
        for (int o = 1; o < 8; o <<= 1) { sum += __shfl_xor(sum, o, 64); sq += __shfl_xor(sq, o, 64); }
        float mu = sum * (1.f / 128.f);
        float var = sq * (1.f / 128.f) - mu * mu;
        float rs = rsqrtf(var + EPSf);
        #pragma unroll
        for (int j = 0; j < 16; ++j) {
            int col = s * 16 + j;
            float a = (vals[j] - mu) * rs * g[col] + bt[col];
            row[col] = a > 0.f ? a : 0.f;
        }
    }
    __syncthreads();

    #pragma unroll
    for (int e = 0; e < 16; ++e) acc[e] = 0.f;
    for (int k = 0; k < 128; k += 4) {
        float w0 = W2[(k + 0) * 128 + c], w1 = W2[(k + 1) * 128 + c];
        float w2 = W2[(k + 2) * 128 + c], w3 = W2[(k + 3) * 128 + c];
        #pragma unroll
        for (int e = 0; e < 16; ++e) {
            float4 a = *(const float4*)(sY + (eg + e) * 128 + k);
            acc[e] += a.x * w0 + a.y * w1 + a.z * w2 + a.w * w3;
        }
    }
    {
        float bb = b2[c];
        #pragma unroll
        for (int e = 0; e < 16; ++e) {
            int node = n0 + eg + e;
            if (node < NN) q[node * 128 + c] = acc[e] + bb;
        }
    }
}

// ------- per-slot MFMA kernel (CSR-permuted, fused softmax partials) -------
__global__ __launch_bounds__(256, 3) void k_edge(
    const float* __restrict__ x, const unsigned short* __restrict__ h_bf,
    const float* __restrict__ ea, const int* __restrict__ ei,
    const int* __restrict__ perm,
    const unsigned short* __restrict__ Wt1,
    const float* __restrict__ kb1, const float* __restrict__ vb1,
    const float* __restrict__ kg, const float* __restrict__ kbt,
    const float* __restrict__ vg, const float* __restrict__ vbt,
    const unsigned short* __restrict__ kW2t, const float* __restrict__ kb2,
    const unsigned short* __restrict__ vW2t, const float* __restrict__ vb2,
    const float* __restrict__ q,
    float* __restrict__ Dg, float* __restrict__ Pg)
{
    // phase A: kv tile [64 rows][384 halves] (48 16B-chunks/row, xor-swizzled by row&7)
    // phase B: Y tile  [64 rows][256 halves] (bytes 0..32768) + sEX/sV f32 (bytes 32768..40960)
    __shared__ __align__(16) unsigned short sR[64 * 384];
    __shared__ float2 sStats[4 * 64];
    __shared__ float sEA[64 * 4];
    __shared__ float sRel[64 * 3];
    __shared__ float sDist[64];
    __shared__ int   sSrc[64], sDst[64];

    float* sEX = (float*)(sR + 16384);   // [16 heads][64 slots], bytes 32768..36864
    float* sVl = (float*)(sR + 18432);   // [16 heads][64 slots], bytes 36864..40960

    const int tid  = threadIdx.x;
    const int e0   = blockIdx.x * 64;
    const int lane = tid & 63;
    const int wv   = tid >> 6;
    const int rA   = lane & 15;
    const int kq   = lane >> 4;

    if (tid < 64) {
        int slot = e0 + tid;
        int e = perm[slot];
        int s = ei[e], d = ei[EE + e];
        sSrc[tid] = s; sDst[tid] = d;
        float rx = x[d*3+0] - x[s*3+0];
        float ry = x[d*3+1] - x[s*3+1];
        float rz = x[d*3+2] - x[s*3+2];
        sRel[tid*3+0] = rx; sRel[tid*3+1] = ry; sRel[tid*3+2] = rz;
        sDist[tid] = sqrtf(rx*rx + ry*ry + rz*rz);
        float4 eav = *(const float4*)(ea + e * 4);
        sEA[tid*4+0] = eav.x; sEA[tid*4+1] = eav.y;
        sEA[tid*4+2] = eav.z; sEA[tid*4+3] = eav.w;
    }
    __syncthreads();

    // h gather: chunks 0..31 (k' 0..255); chunk<16 -> h[dst], else h[src]
    #pragma unroll
    for (int it = 0; it < 8; ++it) {
        int p = tid + it * 256;
        int r = p >> 5, c = p & 31;
        int node = (c < 16) ? sDst[r] : sSrc[r];
        int cc = c & 15;
        uint4 v = *(const uint4*)(h_bf + node * 128 + cc * 8);
        *(uint4*)(&sR[r * 384 + ((c ^ (r & 7)) << 3)]) = v;
    }
    // ea + dist_feat + zero pad: k' 256..383
    const float step  = 10.0f / 19.0f;
    const float coeff = -0.5f / (step * step);
    #pragma unroll
    for (int it = 0; it < 32; ++it) {
        int p = tid + it * 256;
        int r = p >> 7, i = p & 127;
        int k = 256 + i;
        float val;
        if (i < 4) val = sEA[r*4 + i];
        else if (i < 84) {
            int f = (i - 4) / 20, gg = (i - 4) % 20;
            float dd = sDist[r] - (float)gg * step;
            val = sEA[r*4 + f] * __expf(coeff * dd * dd);
        } else val = 0.f;
        int c = k >> 3;
        sR[r * 384 + ((c ^ (r & 7)) << 3) + (k & 7)] = f2bf(val);
    }
    __syncthreads();

    // ---- layer 1 (transposed): C[n][e]; wave wv owns cols n0..n0+63 ----
    const int n0 = wv * 64;
    f32x4 zf = {0.f, 0.f, 0.f, 0.f};
    f32x4 acc[4][4];   // [nf][ef]
    #pragma unroll
    for (int nf = 0; nf < 4; ++nf)
        #pragma unroll
        for (int ef = 0; ef < 4; ++ef) acc[nf][ef] = zf;

    for (int k0 = 0; k0 < 352; k0 += 32) {
        int cbase = (k0 >> 3) + kq;
        short8 wfr[4], kv[4];
        #pragma unroll
        for (int nf = 0; nf < 4; ++nf)
            wfr[nf] = *(const short8*)(Wt1 + (n0 + nf * 16 + rA) * 352 + k0 + kq * 8);
        #pragma unroll
        for (int ef = 0; ef < 4; ++ef) {
            int r = ef * 16 + rA;
            kv[ef] = *(const short8*)(&sR[r * 384 + ((cbase ^ (r & 7)) << 3)]);
        }
        #pragma unroll
        for (int nf = 0; nf < 4; ++nf)
            #pragma unroll
            for (int ef = 0; ef < 4; ++ef)
                acc[nf][ef] = __builtin_amdgcn_mfma_f32_16x16x32_bf16(wfr[nf], kv[ef], acc[nf][ef], 0, 0, 0);
    }

    // ---- bias add (before LN stats) ----
    {
        const float* bsrc = (wv < 2) ? kb1 : vb1;
        int cb = (wv & 1) * 64;
        #pragma unroll
        for (int nf = 0; nf < 4; ++nf) {
            f32x4 bb = *(const f32x4*)(bsrc + cb + nf * 16 + kq * 4);
            #pragma unroll
            for (int ef = 0; ef < 4; ++ef)
                #pragma unroll
                for (int j = 0; j < 4; ++j) acc[nf][ef][j] += bb[j];
        }
    }

    // ---- in-register LN stats ----
    float sm[4], sq2[4];
    #pragma unroll
    for (int ef = 0; ef < 4; ++ef) {
        float s = 0.f, s2 = 0.f;
        #pragma unroll
        for (int nf = 0; nf < 4; ++nf)
            #pragma unroll
            for (int j = 0; j < 4; ++j) { float v = acc[nf][ef][j]; s += v; s2 += v * v; }
        sm[ef] = s; sq2[ef] = s2;
    }
    #pragma unroll
    for (int ef = 0; ef < 4; ++ef) {
        sm[ef]  += __shfl_xor(sm[ef], 16, 64);  sm[ef]  += __shfl_xor(sm[ef], 32, 64);
        sq2[ef] += __shfl_xor(sq2[ef], 16, 64); sq2[ef] += __shfl_xor(sq2[ef], 32, 64);
    }
    if (kq == 0) {
        #pragma unroll
        for (int ef = 0; ef < 4; ++ef)
            sStats[wv * 64 + ef * 16 + rA] = make_float2(sm[ef], sq2[ef]);
    }
    __syncthreads();   // stats ready; all waves done reading kv region

    // ---- normalize + ReLU + pack -> Y LDS ----
    {
        const float* gp = (wv < 2) ? kg : vg;
        const float* bp = (wv < 2) ? kbt : vbt;
        f32x4 g4[4], b4[4];
        #pragma unroll
        for (int nf = 0; nf < 4; ++nf) {
            int cl = (wv & 1) * 64 + nf * 16 + kq * 4;
            g4[nf] = *(const f32x4*)(gp + cl);
            b4[nf] = *(const f32x4*)(bp + cl);
        }
        #pragma unroll
        for (int ef = 0; ef < 4; ++ef) {
            int e = ef * 16 + rA;
            float2 po = sStats[(wv ^ 1) * 64 + e];
            float mu  = (sm[ef] + po.x) * (1.f / 128.f);
            float var = (sq2[ef] + po.y) * (1.f / 128.f) - mu * mu;
            float rs  = rsqrtf(var + EPSf);
            #pragma unroll
            for (int nf = 0; nf < 4; ++nf) {
                float y[4];
                #pragma unroll
                for (int j = 0; j < 4; ++j) {
                    float f = (acc[nf][ef][j] - mu) * rs * g4[nf][j] + b4[nf][j];
                    y[j] = f > 0.f ? f : 0.f;
                }
                int col = n0 + nf * 16 + kq * 4;
                int ch = col >> 3;
                uint2 pw; pw.x = pk2(y[0], y[1]); pw.y = pk2(y[2], y[3]);
                *(uint2*)(&sR[e * 256 + ((ch ^ (e & 7)) << 3) + (col & 7)]) = pw;
            }
        }
    }
    __syncthreads();

    // ---- layer 2 (k) transposed + fused logits + exp -> sEX ----
    {
        const int n0k = wv * 32;
        f32x4 a2[2][4];
        #pragma unroll
        for (int nf2 = 0; nf2 < 2; ++nf2)
            #pragma unroll
            for (int ef = 0; ef < 4; ++ef) a2[nf2][ef] = zf;
        for (int k0 = 0; k0 < 128; k0 += 32) {
            int cbase = (k0 >> 3) + kq;
            short8 wf2[2], yf[4];
            #pragma unroll
            for (int nf2 = 0; nf2 < 2; ++nf2)
                wf2[nf2] = *(const short8*)(kW2t + (n0k + nf2 * 16 + rA) * 128 + k0 + kq * 8);
            #pragma unroll
            for (int ef = 0; ef < 4; ++ef) {
                int r = ef * 16 + rA;
                yf[ef] = *(const short8*)(&sR[r * 256 + ((cbase ^ (r & 7)) << 3)]);
            }
            #pragma unroll
            for (int nf2 = 0; nf2 < 2; ++nf2)
                #pragma unroll
                for (int ef = 0; ef < 4; ++ef)
                    a2[nf2][ef] = __builtin_amdgcn_mfma_f32_16x16x32_bf16(wf2[nf2], yf[ef], a2[nf2][ef], 0, 0, 0);
        }
        f32x4 bb2[2];
        bb2[0] = *(const f32x4*)(kb2 + n0k + kq * 4);
        bb2[1] = *(const f32x4*)(kb2 + n0k + 16 + kq * 4);
        int dloc[4];
        #pragma unroll
        for (int ef = 0; ef < 4; ++ef) dloc[ef] = sDst[ef * 16 + rA];

        float ps[2][4];
        #pragma unroll
        for (int nf2 = 0; nf2 < 2; ++nf2)
            #pragma unroll
            for (int ef = 0; ef < 4; ++ef) {
                const float* qn = q + dloc[ef] * 128 + n0k + nf2 * 16 + kq * 4;
                f32x4 qv = *(const f32x4*)qn;
                float s = 0.f;
                #pragma unroll
                for (int j = 0; j < 4; ++j) s += qv[j] * (a2[nf2][ef][j] + bb2[nf2][j]);
                ps[nf2][ef] = s;
            }
        #pragma unroll
        for (int nf2 = 0; nf2 < 2; ++nf2)
            #pragma unroll
            for (int ef = 0; ef < 4; ++ef)
                ps[nf2][ef] += __shfl_xor(ps[nf2][ef], 16, 64);

        int h_base = wv * 4 + (kq >> 1);
        #pragma unroll
        for (int nf2 = 0; nf2 < 2; ++nf2)
            #pragma unroll
            for (int ef = 0; ef < 4; ++ef) {
                bool act = ((kq & 1) == 0) ? (ef < 2) : (ef >= 2);
                if (act) {
                    int e = ef * 16 + rA;
                    int hh = h_base + nf2 * 2;
                    sEX[hh * 64 + e] = __expf(ps[nf2][ef] * 0.35355339059327373f);
                }
            }
    }

    // ---- layer 2 (v) transposed: wave wv owns slots wv*16+rA, heads kq*4+j -> sV ----
    {
        f32x4 av = zf;
        int r = wv * 16 + rA;
        for (int k0 = 0; k0 < 128; k0 += 32) {
            int cbase = 16 + (k0 >> 3) + kq;
            short8 yv  = *(const short8*)(&sR[r * 256 + ((cbase ^ (r & 7)) << 3)]);
            short8 wfv = *(const short8*)(vW2t + rA * 128 + k0 + kq * 8);
            av = __builtin_amdgcn_mfma_f32_16x16x32_bf16(wfv, yv, av, 0, 0, 0);
        }
        f32x4 bv = *(const f32x4*)(vb2 + kq * 4);
        #pragma unroll
        for (int j = 0; j < 4; ++j)
            sVl[(kq * 4 + j) * 64 + r] = av[j] + bv[j];
    }
    __syncthreads();

    // ---- segmented scan over 16-slot windows; atomics only at segment ends ----
    {
        const int s    = lane & 15;            // slot within window
        const int quad = lane >> 4;            // head quad (heads quad*4..quad*4+3)
        const int slot = wv * 16 + s;
        const int node = sDst[slot];

        bool fl = (s == 0) || (sDst[slot] != sDst[slot - 1]);
        unsigned long long bal = __ballot(fl);
        unsigned fb = (unsigned)((bal >> (quad * 16)) & 0xFFFFull);

        unsigned pre = fb & ((2u << s) - 1);
        int sstart = 31 - __clz(pre);          // highest flag <= s (bit 0 always set)

        float rx = sRel[slot * 3 + 0], ry = sRel[slot * 3 + 1], rz = sRel[slot * 3 + 2];
        float ex4[4], px[4], py[4], pz[4];
        #pragma unroll
        for (int j = 0; j < 4; ++j) {
            float exv = sEX[(quad * 4 + j) * 64 + slot];
            float vv  = sVl[(quad * 4 + j) * 64 + slot];
            float m = exv * vv;
            ex4[j] = exv; px[j] = m * rx; py[j] = m * ry; pz[j] = m * rz;
        }
        #pragma unroll
        for (int st = 1; st <= 8; st <<= 1) {
            bool take = (s - st >= sstart);
            #pragma unroll
            for (int j = 0; j < 4; ++j) {
                float t0 = __shfl_up(ex4[j], st, 16);
                float t1 = __shfl_up(px[j],  st, 16);
                float t2 = __shfl_up(py[j],  st, 16);
                float t3 = __shfl_up(pz[j],  st, 16);
                if (take) { ex4[j] += t0; px[j] += t1; py[j] += t2; pz[j] += t3; }
            }
        }
        bool isend = (s == 15) || ((fb >> (s + 1)) & 1u);
        if (isend) {
            #pragma unroll
            for (int j = 0; j < 4; ++j) {
                int hh = quad * 4 + j;
                atomicAdd(&Dg[node * 16 + hh], ex4[j]);
                atomicAdd(&Pg[node * 48 + 0 * 16 + hh], px[j]);
                atomicAdd(&Pg[node * 48 + 1 * 16 + hh], py[j]);
                atomicAdd(&Pg[node * 48 + 2 * 16 + hh], pz[j]);
            }
        }
    }
}

// ---------------------- finalize: out = (1/16) sum_h P/D ----------------------
__global__ void k_fin(const float* __restrict__ Dg, const float* __restrict__ Pg,
                      float* __restrict__ out) {
    int n = blockIdx.x * 256 + threadIdx.x;
    if (n >= NN) return;
    float inv[16];
    #pragma unroll
    for (int hq = 0; hq < 4; ++hq) {
        f32x4 d = *(const f32x4*)(Dg + n * 16 + hq * 4);
        #pragma unroll
        for (int j = 0; j < 4; ++j) inv[hq * 4 + j] = (d[j] > 0.f) ? (1.f / d[j]) : 0.f;
    }
    #pragma unroll
    for (int c = 0; c < 3; ++c) {
        float s = 0.f;
        #pragma unroll
        for (int hq = 0; hq < 4; ++hq) {
            f32x4 p = *(const f32x4*)(Pg + n * 48 + c * 16 + hq * 4);
            #pragma unroll
            for (int j = 0; j < 4; ++j) s += p[j] * inv[hq * 4 + j];
        }
        out[n * 3 + c] = s * (1.f / 16.f);
    }
}

extern "C" void kernel_launch(void* const* d_in, const int* in_sizes, int n_in,
                              void* d_out, int out_size, void* d_ws, size_t ws_size,
                              hipStream_t stream) {
    const float* x   = (const float*)d_in[0];
    const float* h   = (const float*)d_in[1];
    const float* ea  = (const float*)d_in[2];
    const int*   ei  = (const int*)d_in[4];
    const float* kW1 = (const float*)d_in[5];
    const float* kb1 = (const float*)d_in[6];
    const float* kg  = (const float*)d_in[7];
    const float* kbt = (const float*)d_in[8];
    const float* kW2 = (const float*)d_in[9];
    const float* kb2 = (const float*)d_in[10];
    const float* vW1 = (const float*)d_in[11];
    const float* vb1 = (const float*)d_in[12];
    const float* vg  = (const float*)d_in[13];
    const float* vbt = (const float*)d_in[14];
    const float* vW2 = (const float*)d_in[15];
    const float* vb2 = (const float*)d_in[16];
    const float* qW1 = (const float*)d_in[17];
    const float* qb1 = (const float*)d_in[18];
    const float* qg  = (const float*)d_in[19];
    const float* qbt = (const float*)d_in[20];
    const float* qW2 = (const float*)d_in[21];
    const float* qb2 = (const float*)d_in[22];

    float* ws = (float*)d_ws;
    float* qbuf = ws;                            // N*128 = 1,280,000 w
    float* Dg   = ws + 1280000;                  // N*16  =   160,000 w
    float* Pg   = ws + 1440000;                  // N*48  =   480,000 w
    unsigned short* h_bf = (unsigned short*)(ws + 1920000);   // N*128 halves (640,000 w)
    unsigned short* Wt1  = (unsigned short*)(ws + 2560000);   // 256*352 halves (45,056 w)
    unsigned short* kW2t = (unsigned short*)(ws + 2605056);   // 128*128 halves (8,192 w)
    unsigned short* vW2t = (unsigned short*)(ws + 2613248);   // 16*128 halves (1,024 w)
    int* cnt  = (int*)(ws + 2614272);            // N
    int* base = (int*)(ws + 2624272);            // N+1
    int* cnt2 = (int*)(ws + 2634273);            // N
    int* perm = (int*)(ws + 2644273);            // E
    float* out = (float*)d_out;

    hipLaunchKernelGGL(k_init0, dim3(1875), dim3(256),  0, stream, cnt, Dg, Pg);
    hipLaunchKernelGGL(k_hist,  dim3(1250), dim3(256),  0, stream, ei, cnt);
    hipLaunchKernelGGL(k_scan,  dim3(1),    dim3(1024), 0, stream, cnt, base, cnt2);
    hipLaunchKernelGGL(k_place, dim3(1250), dim3(256),  0, stream, ei, cnt2, perm);
    hipLaunchKernelGGL(k_prep,  dim3(5424), dim3(256),  0, stream,
                       h, kW1, vW1, kW2, vW2, h_bf, Wt1, kW2t, vW2t);
    hipLaunchKernelGGL(k_qmlp,  dim3(313),  dim3(256),  0, stream,
                       h, qW1, qb1, qg, qbt, qW2, qb2, qbuf);
    hipLaunchKernelGGL(k_edge,  dim3(5000), dim3(256),  0, stream,
                       x, h_bf, ea, ei, perm, Wt1,
                       kb1, vb1, kg, kbt, vg, vbt,
                       kW2t, kb2, vW2t, vb2,
                       qbuf, Dg, Pg);
    hipLaunchKernelGGL(k_fin,   dim3(40),   dim3(256),  0, stream, Dg, Pg, out);
}